// Round 1
// baseline (535.698 us; speedup 1.0000x reference)
//
#include <hip/hip_runtime.h>
#include <hip/hip_bf16.h>
#include <stdint.h>

// Problem constants (B, C, H, W, K) = (16, 64, 192, 192, 3)
#define NB 16
#define NC 64
#define NH 192
#define NW 192
#define NKDIM 576   // 9 taps * 64 ci, tap-major: k = tap*64 + ci

typedef __bf16 bf16x8 __attribute__((ext_vector_type(8)));
typedef __bf16 bf16x4 __attribute__((ext_vector_type(4)));
typedef float  f32x4  __attribute__((ext_vector_type(4)));

static __device__ __forceinline__ __bf16 f2bf(float f) { return (__bf16)f; }

// ---------------------------------------------------------------------------
// Blend W0/W1 per batch into bf16, layout A[b][co][tap*64+ci] (tap-major K).
// ---------------------------------------------------------------------------
__global__ __launch_bounds__(256)
void blend_kernel(const float* __restrict__ W0, const float* __restrict__ W1,
                  const float* __restrict__ DoT, __bf16* __restrict__ A) {
    int idx = blockIdx.x * 256 + threadIdx.x;   // 16*64*576 total, exact grid
    int k   = idx % NKDIM;
    int co  = (idx / NKDIM) % NC;
    int b   = idx / (NKDIM * NC);
    int tap = k >> 6;
    int ci  = k & 63;
    float d  = DoT[b];
    int wi   = (co * NC + ci) * 9 + tap;
    float v  = (1.0f - d) * W0[wi] + d * W1[wi];
    A[idx] = f2bf(v);
}

// ---------------------------------------------------------------------------
// Fused single-pass conv: x fp32 NCHW -> LDS bf16 (transposed, swizzled) ->
// implicit-GEMM MFMA -> out fp32 NCHW.
//
// Block = 512 thr (8 waves). Output tile = 64 co x 4 h rows x 64 w.
// Staged LDS tile = 6 rows x 66 w x 64 ci bf16, layout xs[r][wl][gp][8],
// gp = (ci/8) ^ ((wl>>3)&7)  (16B-granular XOR swizzle; stride 72 bf16/wl).
// Wave: mt = wave&3 -> co tile (16 co), nh = wave>>2 -> row pair (2 rows).
// Per wave: 9 taps x 2 ch x 2 rr x 4 nt = 144 MFMA (16x16x32 bf16).
// A-fragments use a 2-deep rotation (cur + next-tap prefetch) so only 4
// bf16x8 A regs are live -> fits the 128-VGPR budget of (512,4); the L2
// A load latency hides under 16 MFMAs per tap.
// ---------------------------------------------------------------------------
__global__ __launch_bounds__(512, 4)
void conv_fused_kernel(const float* __restrict__ x, const __bf16* __restrict__ A,
                       float* __restrict__ out) {
    __shared__ __align__(16) __bf16 xs[6 * 66 * 72];   // 57024 B -> 2 blocks/CU

    // ---- bijective XCD swizzle: 2304 wg, 8 XCDs -> 288-wg contiguous chunks
    const int lid = blockIdx.x;                 // grid launched 1-D: 2304
    const int swz = (lid & 7) * 288 + (lid >> 3);
    const int b   = swz / 144;                  // 144 tiles per batch image
    const int rem = swz - b * 144;
    const int by  = rem / 3;                    // h tile (48)
    const int bx  = rem - by * 3;               // w tile (3)

    const int h0 = by * 4;
    const int w0 = bx * 64;

    const int tid  = threadIdx.x;
    const int lane = tid & 63;
    const int wave = tid >> 6;

    // ---- stage 6 rows x 66 w x 64 ci: fp32 NCHW -> bf16 LDS (transpose) ----
    // item (r, wl, ci4): read 4 ci planes at consecutive gw (coalesced along
    // w across lanes: 64 lanes x 4B contiguous per plane), pack bf16x4, one
    // 8B LDS write.  Main: 6*64*16 = 6144 items = 12 per thread.  Tail: wl=64,65.
    {
        const float* xb0 = x + (size_t)b * NC * NH * NW;
        #pragma unroll
        for (int it = 0; it < 12; ++it) {
            const int q   = it * 512 + tid;     // 0..6143
            const int r   = q >> 10;            // 0..5
            const int rm  = q & 1023;
            const int wl  = rm & 63;
            const int ci4 = rm >> 6;            // 0..15
            const int gr  = h0 - 1 + r;
            const int gw  = w0 - 1 + wl;        // <= 190, no upper check needed
            const bool ok = (gr >= 0) && (gr < NH) && (gw >= 0);
            const float* xp = xb0 + ((size_t)(ci4 * 4) * NH + gr) * NW + gw;
            float v0 = ok ? xp[0] : 0.0f;
            float v1 = ok ? xp[(size_t)NH * NW] : 0.0f;
            float v2 = ok ? xp[2 * (size_t)NH * NW] : 0.0f;
            float v3 = ok ? xp[3 * (size_t)NH * NW] : 0.0f;
            bf16x4 pk = { f2bf(v0), f2bf(v1), f2bf(v2), f2bf(v3) };
            const int g  = ci4 >> 1;
            const int gp = g ^ ((wl >> 3) & 7);
            *(bf16x4*)&xs[(r * 66 + wl) * 72 + gp * 8 + (ci4 & 1) * 4] = pk;
        }
        if (tid < 192) {                        // 6 r * 16 ci4 * 2 wl
            const int wl  = 64 + (tid & 1);
            const int ci4 = (tid >> 1) & 15;
            const int r   = tid >> 5;
            const int gr  = h0 - 1 + r;
            const int gw  = w0 - 1 + wl;        // >= 63, no lower check needed
            const bool ok = (gr >= 0) && (gr < NH) && (gw < NW);
            const float* xp = xb0 + ((size_t)(ci4 * 4) * NH + gr) * NW + gw;
            float v0 = ok ? xp[0] : 0.0f;
            float v1 = ok ? xp[(size_t)NH * NW] : 0.0f;
            float v2 = ok ? xp[2 * (size_t)NH * NW] : 0.0f;
            float v3 = ok ? xp[3 * (size_t)NH * NW] : 0.0f;
            bf16x4 pk = { f2bf(v0), f2bf(v1), f2bf(v2), f2bf(v3) };
            const int g  = ci4 >> 1;
            const int gp = g ^ ((wl >> 3) & 7); // wl>>3 == 8 -> &7 == 0
            *(bf16x4*)&xs[(r * 66 + wl) * 72 + gp * 8 + (ci4 & 1) * 4] = pk;
        }
    }

    // ---- per-wave geometry ----
    const int mt   = wave & 3;    // co tile: co = mt*16 .. +16
    const int nh   = wave >> 2;   // row pair: output rows h0 + nh*2 + {0,1}
    const int n    = lane & 15;
    const int quad = lane >> 4;

    // A[m=lane&15][k=quad*8+j] (m89-verified), k = tap*64 + ch*32 + quad*8 + j
    const __bf16* Ap = A + ((size_t)b * NC + mt * 16 + n) * NKDIM + quad * 8;
    bf16x8 a0 = *(const bf16x8*)(Ap + 0);
    bf16x8 a1 = *(const bf16x8*)(Ap + 32);

    f32x4 acc[2][4];
    #pragma unroll
    for (int rr = 0; rr < 2; ++rr)
        #pragma unroll
        for (int nt = 0; nt < 4; ++nt)
            acc[rr][nt] = (f32x4){0.f, 0.f, 0.f, 0.f};

    __syncthreads();

    // ---- MFMA main loop: 9 taps x (2 ch x 2 rr x 4 nt) = 144 MFMA/wave ----
    #pragma unroll
    for (int tap = 0; tap < 9; ++tap) {
        const int tn = (tap < 8) ? tap + 1 : 8;         // next-tap prefetch
        const bf16x8 na0 = *(const bf16x8*)(Ap + tn * 64);
        const bf16x8 na1 = *(const bf16x8*)(Ap + tn * 64 + 32);

        const int dh = tap / 3;
        const int dw = tap - dh * 3;
        #pragma unroll
        for (int rr = 0; rr < 2; ++rr) {
            const int row = nh * 2 + rr + dh;           // staged row 0..5
            #pragma unroll
            for (int nt = 0; nt < 4; ++nt) {
                const int wl = dw + nt * 16 + n;
                const int sw = (wl >> 3) & 7;
                const int base = (row * 66 + wl) * 72;
                bf16x8 b0 = *(const bf16x8*)&xs[base + ((0 * 4 + quad) ^ sw) * 8];
                bf16x8 b1 = *(const bf16x8*)&xs[base + ((1 * 4 + quad) ^ sw) * 8];
                acc[rr][nt] = __builtin_amdgcn_mfma_f32_16x16x32_bf16(
                    a0, b0, acc[rr][nt], 0, 0, 0);
                acc[rr][nt] = __builtin_amdgcn_mfma_f32_16x16x32_bf16(
                    a1, b1, acc[rr][nt], 0, 0, 0);
            }
        }
        a0 = na0; a1 = na1;
    }

    // ---- epilogue: D col=lane&15 (w), row=quad*4+reg (co within tile) ----
    #pragma unroll
    for (int rr = 0; rr < 2; ++rr) {
        const int h = h0 + nh * 2 + rr;
        float* ob = out + (size_t)b * NC * NH * NW + (size_t)h * NW + w0;
        #pragma unroll
        for (int reg = 0; reg < 4; ++reg) {
            const int co = mt * 16 + quad * 4 + reg;
            float* orow = ob + (size_t)co * NH * NW;
            #pragma unroll
            for (int nt = 0; nt < 4; ++nt) {
                orow[nt * 16 + n] = acc[rr][nt][reg];
            }
        }
    }
}

// ---------------------------------------------------------------------------
extern "C" void kernel_launch(void* const* d_in, const int* in_sizes, int n_in,
                              void* d_out, int out_size, void* d_ws, size_t ws_size,
                              hipStream_t stream) {
    const float* x   = (const float*)d_in[0];
    const float* DoT = (const float*)d_in[1];
    const float* W0  = (const float*)d_in[2];
    const float* W1  = (const float*)d_in[3];
    float* out = (float*)d_out;

    // Workspace: only A (blended bf16 weights), 16*64*576*2 = 1,179,648 B.
    __bf16* A = (__bf16*)d_ws;

    blend_kernel<<<dim3((NB * NC * NKDIM) / 256), 256, 0, stream>>>(W0, W1, DoT, A);

    // 2304 workgroups = 16 b * 48 h-tiles * 3 w-tiles, XCD-swizzled in-kernel.
    conv_fused_kernel<<<dim3(2304, 1, 1), dim3(512), 0, stream>>>(x, A, out);
}

// Round 4
// 444.273 us; speedup vs baseline: 1.2058x; 1.2058x over previous
//
#include <hip/hip_runtime.h>
#include <hip/hip_bf16.h>
#include <stdint.h>

// Problem constants (B, C, H, W, K) = (16, 64, 192, 192, 3)
#define NB 16
#define NC 64
#define NH 192
#define NW 192
#define NKDIM 576   // 9 taps * 64 ci, tap-major: k = tap*64 + ci

typedef __bf16 bf16x8 __attribute__((ext_vector_type(8)));
typedef __bf16 bf16x4 __attribute__((ext_vector_type(4)));
typedef float  f32x4  __attribute__((ext_vector_type(4)));

static __device__ __forceinline__ __bf16 f2bf(float f) { return (__bf16)f; }

// ---------------------------------------------------------------------------
// Blend W0/W1 per batch into bf16, layout A[b][co][tap*64+ci] (tap-major K).
// ---------------------------------------------------------------------------
__global__ __launch_bounds__(256)
void blend_kernel(const float* __restrict__ W0, const float* __restrict__ W1,
                  const float* __restrict__ DoT, __bf16* __restrict__ A) {
    int idx = blockIdx.x * 256 + threadIdx.x;   // 16*64*576 total, exact grid
    int k   = idx % NKDIM;
    int co  = (idx / NKDIM) % NC;
    int b   = idx / (NKDIM * NC);
    int tap = k >> 6;
    int ci  = k & 63;
    float d  = DoT[b];
    int wi   = (co * NC + ci) * 9 + tap;
    float v  = (1.0f - d) * W0[wi] + d * W1[wi];
    A[idx] = f2bf(v);
}

// ---------------------------------------------------------------------------
// Pass 1: x NCHW fp32 -> xt NHWC bf16.  Block = 256 thr, tile = 64 ci x 64 w
// for one (b,h).  LDS fp32 tile [w][ci] stride 68 (16B-aligned, bank-uniform).
// (verbatim from the verified 373us version)
// ---------------------------------------------------------------------------
__global__ __launch_bounds__(256)
void nhwc_cvt_kernel(const float* __restrict__ x, __bf16* __restrict__ xt) {
    __shared__ float tile[64 * 68];   // 17408 B

    const int b  = blockIdx.z;
    const int h  = blockIdx.y;
    const int wt = blockIdx.x * 64;
    const int t  = threadIdx.x;

    // read phase: thread (ci = t&63, wq = t>>6) loads 4 float4 along w
    {
        const int ci = t & 63;
        const int wq = t >> 6;
        const float* src = x + ((size_t)(b * NC + ci) * NH + h) * NW + wt;
        #pragma unroll
        for (int w4l = 0; w4l < 4; ++w4l) {
            const int w4 = wq * 4 + w4l;
            f32x4 v = *(const f32x4*)(src + w4 * 4);
            #pragma unroll
            for (int j = 0; j < 4; ++j)
                tile[(w4 * 4 + j) * 68 + ci] = v[j];
        }
    }
    __syncthreads();

    // write phase: chunk c -> (w = c>>3, cig = c&7); 8 ci -> bf16x8 store
    __bf16* dst = xt + ((size_t)(b * NH + h) * NW + wt) * NC;
    #pragma unroll
    for (int it = 0; it < 2; ++it) {
        const int c   = it * 256 + t;
        const int w   = c >> 3;
        const int cig = c & 7;
        f32x4 v0 = *(const f32x4*)&tile[w * 68 + cig * 8];
        f32x4 v1 = *(const f32x4*)&tile[w * 68 + cig * 8 + 4];
        bf16x8 pk = { f2bf(v0[0]), f2bf(v0[1]), f2bf(v0[2]), f2bf(v0[3]),
                      f2bf(v1[0]), f2bf(v1[1]), f2bf(v1[2]), f2bf(v1[3]) };
        *(bf16x8*)(dst + (size_t)w * NC + cig * 8) = pk;
    }
}

// ---------------------------------------------------------------------------
// Pass 2: implicit-GEMM conv from NHWC bf16.  Block = 512 thr (8 waves) ->
// 64 co x (4 rows x 64 w).  Staged LDS = 6 rows x 66 w x 64 ci bf16,
// layout xs[r][w][g'][8], g' = g ^ (w&7): both ds_write_b128 (staging) and
// ds_read_b128 (main loop) bank-uniform -> 0 conflicts (measured round-0).
// Wave: mt = wave&3 -> co tile (16 co), nh = wave>>2 -> row pair.
// A-fragments: 2-deep rotation (cur tap + next-tap prefetch, 16 VGPRs) so
// the whole loop fits the 128-VGPR budget of (512,4) with no L2-latency
// stall chained into the MFMAs (round-0's afr[9][2] did not fit: VGPR=60
// meant A loads were sunk into the loop -> MfmaUtil 15%).
// Per wave: 9 taps x 2 ch x 2 rr x 4 nt = 144 MFMA (16x16x32 bf16).
// ---------------------------------------------------------------------------
__global__ __launch_bounds__(512, 4)
void conv_nhwc_kernel(const __bf16* __restrict__ xt, const __bf16* __restrict__ A,
                      float* __restrict__ out) {
    __shared__ __align__(16) __bf16 xs[6 * 66 * 8 * 8];   // 50688 B -> 2 blk/CU

    const int b  = blockIdx.z;
    const int h0 = blockIdx.y * 4;
    const int w0 = blockIdx.x * 64;

    const int tid  = threadIdx.x;
    const int lane = tid & 63;
    const int wave = tid >> 6;

    // ---- stage 6 rows x 66 w x 64 ci (bf16, 16B chunks, swizzled) ----
    // 3168 chunks: chunk c -> r = c/528, w = (c%528)>>3, g = c&7
    {
        #pragma unroll
        for (int it = 0; it < 6; ++it) {
            const int c   = it * 512 + tid;     // 0..3071
            const int r   = c / 528;
            const int rem = c - r * 528;
            const int w   = rem >> 3;
            const int g   = rem & 7;
            const int gr  = h0 - 1 + r;
            const int gw  = w0 - 1 + w;
            const bool ok = (gr >= 0) && (gr < NH) && (gw >= 0) && (gw < NW);
            bf16x8 v = {};
            if (ok)
                v = *(const bf16x8*)(xt + ((size_t)(b * NH + gr) * NW + gw) * NC + g * 8);
            *(bf16x8*)&xs[(((r * 66 + w) * 8) + (g ^ (w & 7))) * 8] = v;
        }
        if (tid < 96) {                         // tail: chunks 3072..3167
            const int r   = 5;
            const int rem = 432 + tid;          // 432..527
            const int w   = rem >> 3;           // 54..65
            const int g   = rem & 7;
            const int gr  = h0 + 4;             // r=5 -> gr = h0-1+5
            const int gw  = w0 - 1 + w;         // >= 53, no lower check needed
            const bool ok = (gr < NH) && (gw < NW);
            bf16x8 v = {};
            if (ok)
                v = *(const bf16x8*)(xt + ((size_t)(b * NH + gr) * NW + gw) * NC + g * 8);
            *(bf16x8*)&xs[(((r * 66 + w) * 8) + (g ^ (w & 7))) * 8] = v;
        }
    }

    // ---- per-wave geometry ----
    const int mt   = wave & 3;    // co tile: co = mt*16 .. +16
    const int nh   = wave >> 2;   // row pair: output rows h0 + nh*2 + {0,1}
    const int n    = lane & 15;
    const int quad = lane >> 4;

    // A[m=lane&15][k=quad*8+j] (m89-verified), k = tap*64 + ch*32 + quad*8 + j
    const __bf16* Ap = A + ((size_t)b * NC + mt * 16 + n) * NKDIM + quad * 8;
    bf16x8 a0 = *(const bf16x8*)(Ap + 0);
    bf16x8 a1 = *(const bf16x8*)(Ap + 32);

    f32x4 acc[2][4];
    #pragma unroll
    for (int rr = 0; rr < 2; ++rr)
        #pragma unroll
        for (int nt = 0; nt < 4; ++nt)
            acc[rr][nt] = (f32x4){0.f, 0.f, 0.f, 0.f};

    __syncthreads();

    // ---- MFMA main loop: 9 taps x (2 rr x 4 nt x 2 ch) = 144 MFMA/wave ----
    #pragma unroll
    for (int tap = 0; tap < 9; ++tap) {
        const int tn = (tap < 8) ? tap + 1 : 8;         // next-tap prefetch
        const bf16x8 na0 = *(const bf16x8*)(Ap + tn * 64);
        const bf16x8 na1 = *(const bf16x8*)(Ap + tn * 64 + 32);

        const int dh = tap / 3;
        const int dw = tap - dh * 3;
        #pragma unroll
        for (int rr = 0; rr < 2; ++rr) {
            const int row = nh * 2 + rr + dh;           // staged row 0..5
            #pragma unroll
            for (int nt = 0; nt < 4; ++nt) {
                const int wl = dw + nt * 16 + n;
                const int sw = wl & 7;
                const int base = ((row * 66 + wl) * 8) * 8;
                bf16x8 b0 = *(const bf16x8*)&xs[base + ((0 * 4 + quad) ^ sw) * 8];
                acc[rr][nt] = __builtin_amdgcn_mfma_f32_16x16x32_bf16(
                    a0, b0, acc[rr][nt], 0, 0, 0);
                bf16x8 b1 = *(const bf16x8*)&xs[base + ((1 * 4 + quad) ^ sw) * 8];
                acc[rr][nt] = __builtin_amdgcn_mfma_f32_16x16x32_bf16(
                    a1, b1, acc[rr][nt], 0, 0, 0);
            }
        }
        a0 = na0; a1 = na1;
    }

    // ---- epilogue: D col=lane&15 (w), row=quad*4+reg (co within tile) ----
    #pragma unroll
    for (int rr = 0; rr < 2; ++rr) {
        const int h = h0 + nh * 2 + rr;
        float* ob = out + (size_t)b * NC * NH * NW + (size_t)h * NW + w0;
        #pragma unroll
        for (int reg = 0; reg < 4; ++reg) {
            const int co = mt * 16 + quad * 4 + reg;
            float* orow = ob + (size_t)co * NH * NW;
            #pragma unroll
            for (int nt = 0; nt < 4; ++nt) {
                orow[nt * 16 + n] = acc[rr][nt][reg];
            }
        }
    }
}

// ---------------------------------------------------------------------------
// Fallback (verified single-pass NCHW kernel) if ws_size is too small for xt.
// ---------------------------------------------------------------------------
__global__ __launch_bounds__(512, 4)
void conv_nchw_kernel(const float* __restrict__ x, const __bf16* __restrict__ A,
                      float* __restrict__ out) {
    __shared__ __bf16 xs[4 * 66 * 72];

    const int b  = blockIdx.z;
    const int h0 = blockIdx.y * 2;
    const int w0 = blockIdx.x * 64;

    const int tid  = threadIdx.x;
    const int lane = tid & 63;
    const int wave = tid >> 6;

    {
        const int r  = tid >> 7;
        const int s  = tid & 127;
        const int gr = h0 - 1 + r;
        const bool rowok = (gr >= 0) && (gr < NH);
        const float* xb = x + (size_t)b * NC * NH * NW + (ptrdiff_t)gr * NW;

        #pragma unroll
        for (int j = 0; j < 8; ++j) {
            const int p   = j * 128 + s;
            const int wl  = p & 63;
            const int ci4 = p >> 6;
            const int gw  = w0 - 1 + wl;
            const bool ok = rowok && (gw >= 0);
            float v0 = ok ? xb[(size_t)(ci4 * 4 + 0) * NH * NW + gw] : 0.0f;
            float v1 = ok ? xb[(size_t)(ci4 * 4 + 1) * NH * NW + gw] : 0.0f;
            float v2 = ok ? xb[(size_t)(ci4 * 4 + 2) * NH * NW + gw] : 0.0f;
            float v3 = ok ? xb[(size_t)(ci4 * 4 + 3) * NH * NW + gw] : 0.0f;
            bf16x4 pk = { f2bf(v0), f2bf(v1), f2bf(v2), f2bf(v3) };
            const int g  = ci4 >> 1;
            const int gp = g ^ ((wl >> 3) & 7);
            *(bf16x4*)&xs[(r * 66 + wl) * 72 + gp * 8 + (ci4 & 1) * 4] = pk;
        }
        if (s < 32) {
            const int wl  = 64 + (s & 1);
            const int ci4 = s >> 1;
            const int gw  = w0 - 1 + wl;
            const bool ok = rowok && (gw < NW);
            float v0 = ok ? xb[(size_t)(ci4 * 4 + 0) * NH * NW + gw] : 0.0f;
            float v1 = ok ? xb[(size_t)(ci4 * 4 + 1) * NH * NW + gw] : 0.0f;
            float v2 = ok ? xb[(size_t)(ci4 * 4 + 2) * NH * NW + gw] : 0.0f;
            float v3 = ok ? xb[(size_t)(ci4 * 4 + 3) * NH * NW + gw] : 0.0f;
            bf16x4 pk = { f2bf(v0), f2bf(v1), f2bf(v2), f2bf(v3) };
            const int g  = ci4 >> 1;
            const int gp = g ^ ((wl >> 3) & 7);
            *(bf16x4*)&xs[(r * 66 + wl) * 72 + gp * 8 + (ci4 & 1) * 4] = pk;
        }
    }

    const int mt   = wave & 3;
    const int nh   = wave >> 2;
    const int n    = lane & 15;
    const int quad = lane >> 4;

    const __bf16* Ap = A + ((size_t)b * NC + mt * 16 + n) * NKDIM + quad * 8;
    bf16x8 afr[9][2];
    #pragma unroll
    for (int tap = 0; tap < 9; ++tap)
        #pragma unroll
        for (int ch = 0; ch < 2; ++ch)
            afr[tap][ch] = *(const bf16x8*)(Ap + tap * 64 + ch * 32);

    __syncthreads();

    f32x4 acc[4];
    #pragma unroll
    for (int nt = 0; nt < 4; ++nt) acc[nt] = (f32x4){0.f, 0.f, 0.f, 0.f};

    #pragma unroll
    for (int tap = 0; tap < 9; ++tap) {
        const int dh  = tap / 3;
        const int dw  = tap - dh * 3;
        const int row = nh + dh;
        #pragma unroll
        for (int ch = 0; ch < 2; ++ch) {
            const int g = ch * 4 + quad;
            #pragma unroll
            for (int nt = 0; nt < 4; ++nt) {
                const int wl = dw + nt * 16 + n;
                const int gp = g ^ ((wl >> 3) & 7);
                bf16x8 bfr = *(const bf16x8*)&xs[(row * 66 + wl) * 72 + gp * 8];
                acc[nt] = __builtin_amdgcn_mfma_f32_16x16x32_bf16(
                    afr[tap][ch], bfr, acc[nt], 0, 0, 0);
            }
        }
    }

    const int h = h0 + nh;
    float* ob = out + (size_t)b * NC * NH * NW + (size_t)h * NW + w0;
    #pragma unroll
    for (int reg = 0; reg < 4; ++reg) {
        const int co = mt * 16 + quad * 4 + reg;
        float* orow = ob + (size_t)co * NH * NW;
        #pragma unroll
        for (int nt = 0; nt < 4; ++nt) {
            orow[nt * 16 + n] = acc[nt][reg];
        }
    }
}

// ---------------------------------------------------------------------------
extern "C" void kernel_launch(void* const* d_in, const int* in_sizes, int n_in,
                              void* d_out, int out_size, void* d_ws, size_t ws_size,
                              hipStream_t stream) {
    const float* x   = (const float*)d_in[0];
    const float* DoT = (const float*)d_in[1];
    const float* W0  = (const float*)d_in[2];
    const float* W1  = (const float*)d_in[3];
    float* out = (float*)d_out;

    // Workspace layout: A (blended bf16 weights) then xt (NHWC bf16 x).
    const size_t A_BYTES  = (size_t)NB * NC * NKDIM * 2;          // 1,179,648
    const size_t XT_BYTES = (size_t)NB * NH * NW * NC * 2;        // 75,497,472
    __bf16* A  = (__bf16*)d_ws;
    __bf16* xt = (__bf16*)((char*)d_ws + A_BYTES);

    blend_kernel<<<dim3((NB * NC * NKDIM) / 256), 256, 0, stream>>>(W0, W1, DoT, A);

    if (ws_size >= A_BYTES + XT_BYTES) {
        nhwc_cvt_kernel<<<dim3(NW / 64, NH, NB), dim3(256), 0, stream>>>(x, xt);
        conv_nhwc_kernel<<<dim3(NW / 64, NH / 4, NB), dim3(512), 0, stream>>>(xt, A, out);
    } else {
        conv_nchw_kernel<<<dim3(NW / 64, NH / 2, NB), dim3(512), 0, stream>>>(x, A, out);
    }
}